// Round 5
// baseline (532.513 us; speedup 1.0000x reference)
//
#include <hip/hip_runtime.h>

#define N_ROWS 32768
#define HDIM 1024
#define NCLS 1000
#define CPAD 1024
#define NOUT 1024
#define KK2 2048

typedef __attribute__((ext_vector_type(8))) unsigned short ushort8v;
typedef __attribute__((ext_vector_type(4))) unsigned short ushort4v;
typedef __attribute__((ext_vector_type(8))) _Float16 f16x8;
typedef __attribute__((ext_vector_type(4))) float f32x4;

#define WAITVM(n) asm volatile("s_waitcnt vmcnt(" #n ")" ::: "memory")
#define LGKM(n) do { asm volatile("s_waitcnt lgkmcnt(" #n ")" ::: "memory"); \
                     __builtin_amdgcn_sched_barrier(0); } while (0)
#define BAR() __builtin_amdgcn_s_barrier()
#define SCHED0() __builtin_amdgcn_sched_barrier(0)

__device__ inline unsigned short h_bits(_Float16 h) {
  union { _Float16 h; unsigned short u; } c; c.h = h; return c.u;
}

__device__ inline unsigned long long shfl_xor_u64(unsigned long long v, int m) {
  int lo = __shfl_xor((int)(unsigned)(v & 0xFFFFFFFFull), m, 64);
  int hi = __shfl_xor((int)(unsigned)(v >> 32), m, 64);
  return ((unsigned long long)(unsigned)hi << 32) | (unsigned)lo;
}

// async global -> LDS, 16B per lane. LDS dest is wave-uniform base + lane*16.
__device__ __forceinline__ void gload16(const void* g, void* l) {
  __builtin_amdgcn_global_load_lds(
      (__attribute__((address_space(1))) void*)g,
      (__attribute__((address_space(3))) void*)l, 16, 0, 0);
}

__global__ __launch_bounds__(256) void init_keys_kernel(unsigned long long* __restrict__ keys) {
  keys[(size_t)blockIdx.x * 256 + threadIdx.x] = 0ull;
}

// One block per (padded) anchor row: norm, scale by 1024/max(norm,eps), fp16 hi/lo split.
__global__ __launch_bounds__(256) void prep_anchors_kernel(
    const float* __restrict__ anchors, unsigned short* __restrict__ ash,
    unsigned short* __restrict__ asl, unsigned short* __restrict__ anh) {
  int c = blockIdx.x;
  int t = threadIdx.x;
  float v[4];
  float ss = 0.f;
  if (c < NCLS) {
    for (int i = 0; i < 4; i++) {
      v[i] = anchors[(size_t)c * HDIM + (i << 8) + t];
      ss += v[i] * v[i];
    }
  } else {
    v[0] = v[1] = v[2] = v[3] = 0.f;
  }
  for (int m = 1; m < 64; m <<= 1) ss += __shfl_xor(ss, m, 64);
  __shared__ float wsum[4];
  if ((t & 63) == 0) wsum[t >> 6] = ss;
  __syncthreads();
  float tot = wsum[0] + wsum[1] + wsum[2] + wsum[3];
  float scale = 1024.0f / fmaxf(sqrtf(tot), 1e-8f);
  for (int i = 0; i < 4; i++) {
    float x = v[i] * scale;
    _Float16 hi = (_Float16)x;
    float lo = x - (float)hi;
    size_t o = (size_t)c * HDIM + (i << 8) + t;
    ash[o] = h_bits(hi);
    asl[o] = h_bits((_Float16)lo);
    anh[o] = h_bits((_Float16)v[i]);
  }
}

// features fp32 -> fp16 hi + fp16 lo, vectorized
__global__ __launch_bounds__(256) void fsplit_kernel(const float* __restrict__ f,
    unsigned short* __restrict__ fh, unsigned short* __restrict__ fl) {
  size_t i = (size_t)blockIdx.x * 256 + threadIdx.x;
  float4 v = reinterpret_cast<const float4*>(f)[i];
  float xs[4] = {v.x, v.y, v.z, v.w};
  ushort4v h, l;
  for (int j = 0; j < 4; j++) {
    _Float16 hi = (_Float16)xs[j];
    float lo = xs[j] - (float)hi;
    h[j] = h_bits(hi);
    l[j] = h_bits((_Float16)lo);
  }
  reinterpret_cast<ushort4v*>(fh)[i] = h;
  reinterpret_cast<ushort4v*>(fl)[i] = l;
}

// W [2048,1024] fp32 row-major -> Wt [1024,2048] fp16 (k contiguous), via LDS transpose
__global__ __launch_bounds__(256) void wtrans_kernel(const float* __restrict__ W,
                                                     unsigned short* __restrict__ Wt) {
  __shared__ float tile[64][65];
  int kb = (blockIdx.x >> 4) << 6;
  int nb = (blockIdx.x & 15) << 6;
  int t = threadIdx.x;
  int tc = t & 63, tr = t >> 6;
  for (int i = 0; i < 16; i++) {
    int r = (i << 2) + tr;
    tile[r][tc] = W[(size_t)(kb + r) * NOUT + nb + tc];
  }
  __syncthreads();
  for (int i = 0; i < 16; i++) {
    int r = (i << 2) + tr;
    Wt[(size_t)(nb + r) * KK2 + kb + tc] = h_bits((_Float16)tile[tc][r]);
  }
}

// ---------------- 128x128 4-wave kernel (kept for anchor_proj: tiny grid) ----------------
__global__ __launch_bounds__(256) void gemm_out_kernel(
    const unsigned short* __restrict__ Ahi, const unsigned short* __restrict__ Bhi,
    int lda, int ldb, int bkoff, int NT, float* __restrict__ Dout, int ldd) {
  __shared__ unsigned short sA[128 * 32];
  __shared__ unsigned short sB[128 * 32];
  int t = threadIdx.x;
  int bidx = blockIdx.x;
  int nt = bidx % NT, mt = bidx / NT;
  int mbase = mt << 7, nbase = nt << 7;
  int lane = t & 63, wid = t >> 6;
  int wy = wid >> 1, wx = wid & 1;
  int lr = lane & 15;
  int lk2 = (((lane >> 4) ^ ((lane >> 1) & 3)) << 3);
  int crow = lane >> 2;
  int celsw = (((lane & 3) ^ ((lane >> 3) & 3)) << 3);
  int c0 = wid << 1;

  const unsigned short* pa0 = Ahi + (size_t)(mbase + (c0 << 4) + crow) * lda + celsw;
  const unsigned short* pa1 = pa0 + (size_t)16 * lda;
  const unsigned short* pb0 = Bhi + (size_t)(nbase + (c0 << 4) + crow) * ldb + bkoff + celsw;
  const unsigned short* pb1 = pb0 + (size_t)16 * ldb;
  unsigned short* dA0 = &sA[(size_t)c0 << 9];
  unsigned short* dA1 = &sA[(size_t)(c0 + 1) << 9];
  unsigned short* dB0 = &sB[(size_t)c0 << 9];
  unsigned short* dB1 = &sB[(size_t)(c0 + 1) << 9];

  f32x4 zero = {0.f, 0.f, 0.f, 0.f};
  f32x4 acc[4][4];
  for (int i = 0; i < 4; i++)
    for (int j = 0; j < 4; j++) acc[i][j] = zero;

  for (int k0 = 0; k0 < HDIM; k0 += 32) {
    gload16(pa0 + k0, dA0);
    gload16(pa1 + k0, dA1);
    gload16(pb0 + k0, dB0);
    gload16(pb1 + k0, dB1);
    __syncthreads();
    f16x8 ah[4], bh[4];
    for (int i = 0; i < 4; i++) {
      int ar = (wy << 6) + (i << 4) + lr;
      int br = (wx << 6) + (i << 4) + lr;
      ah[i] = *reinterpret_cast<const f16x8*>(&sA[ar * 32 + lk2]);
      bh[i] = *reinterpret_cast<const f16x8*>(&sB[br * 32 + lk2]);
    }
    for (int i = 0; i < 4; i++)
      for (int j = 0; j < 4; j++)
        acc[i][j] = __builtin_amdgcn_mfma_f32_16x16x32_f16(ah[i], bh[j], acc[i][j], 0, 0, 0);
    __syncthreads();
  }

  int q = lane >> 4, cc = lane & 15;
  for (int i = 0; i < 4; i++)
    for (int r = 0; r < 4; r++) {
      int grow = mbase + (wy << 6) + (i << 4) + (q << 2) + r;
      for (int j = 0; j < 4; j++) {
        int gcol = nbase + (wx << 6) + (j << 4) + cc;
        Dout[(size_t)grow * ldd + gcol] = acc[i][j][r];
      }
    }
}

// ---------------- SIM: 256x256, 8 waves, 2 LDS bufs, cross-phase read prefetch ----------------
// (unchanged from R4 — measured 198 µs, MfmaUtil 46, conflicts 0)
__global__ __launch_bounds__(512, 2) void gemm256_sim(
    const unsigned short* __restrict__ Ahi, const unsigned short* __restrict__ Alo,
    const unsigned short* __restrict__ Bhi, const unsigned short* __restrict__ Blo,
    int lda, int ldb, int NT,
    unsigned long long* __restrict__ keys) {
  __shared__ unsigned short lds[65536];
  constexpr int AH = 0, AL = 8192, BH = 16384, BL = 24576, BUF = 32768;

  int t = threadIdx.x;
  int bidx = blockIdx.x;
  int xcd = bidx & 7, slot = bidx >> 3;
  int nt = slot % NT, mt = (slot / NT) * 8 + xcd;
  int mbase = mt << 8, nbase = nt << 8;
  int lane = t & 63, wid = t >> 6;
  int wy = wid >> 2, wx = wid & 3;
  int lr = lane & 15;
  int lk2 = (((lane >> 4) ^ ((lane >> 1) & 3)) << 3);

  int srow = (wid << 4) + (lane >> 2);
  int scol = (((lane & 3) ^ ((lane >> 3) & 3)) << 3);
  int wdst = wid << 9;

  const unsigned short* gAh = Ahi + (size_t)(mbase + srow) * lda + scol;
  const unsigned short* gBh = Bhi + (size_t)(nbase + srow) * ldb + scol;
  const unsigned short* gAl = Alo + (gAh - Ahi);
  const unsigned short* gBl = Blo + (gBh - Bhi);
  const size_t a128 = (size_t)128 * lda, b128 = (size_t)128 * ldb;

  auto STAGE = [&](int k0v, int cb) {
    int co = cb * BUF;
    gload16(gAh + k0v, &lds[AH + co + wdst]);
    gload16(gAh + a128 + k0v, &lds[AH + co + 4096 + wdst]);
    gload16(gBh + k0v, &lds[BH + co + wdst]);
    gload16(gBh + b128 + k0v, &lds[BH + co + 4096 + wdst]);
    gload16(gBl + k0v, &lds[BL + co + wdst]);
    gload16(gBl + b128 + k0v, &lds[BL + co + 4096 + wdst]);
    gload16(gAl + k0v, &lds[AL + co + wdst]);
    gload16(gAl + a128 + k0v, &lds[AL + co + 4096 + wdst]);
  };

  int arowb = (((wy << 7) + lr) << 5) + lk2;
  int browb = (((wx << 6) + lr) << 5) + lk2;

  f32x4 zero = {0.f, 0.f, 0.f, 0.f};
  f32x4 acc[8][4];
#pragma unroll
  for (int i = 0; i < 8; i++)
#pragma unroll
    for (int j = 0; j < 4; j++) acc[i][j] = zero;

  STAGE(0, 0);
  STAGE(32, 1);
  WAITVM(8);
  BAR();

  f16x8 ah[8], bh[4], al[8], bl[4];
#pragma unroll
  for (int i = 0; i < 8; i++)
    ah[i] = *reinterpret_cast<const f16x8*>(&lds[AH + arowb + (i << 9)]);
#pragma unroll
  for (int j = 0; j < 4; j++)
    bh[j] = *reinterpret_cast<const f16x8*>(&lds[BH + browb + (j << 9)]);

  for (int tt = 0; tt < 32; ++tt) {
    int co = (tt & 1) * BUF;
    int cn = ((tt + 1) & 1) * BUF;
    LGKM(0);
    __builtin_amdgcn_s_setprio(1);
#pragma unroll
    for (int i = 0; i < 8; i++)
#pragma unroll
      for (int j = 0; j < 4; j++)
        acc[i][j] = __builtin_amdgcn_mfma_f32_16x16x32_f16(ah[i], bh[j], acc[i][j], 0, 0, 0);
    __builtin_amdgcn_s_setprio(0);
    SCHED0();
#pragma unroll
    for (int j = 0; j < 4; j++)
      bl[j] = *reinterpret_cast<const f16x8*>(&lds[BL + co + browb + (j << 9)]);
#pragma unroll
    for (int i = 0; i < 8; i++)
      al[i] = *reinterpret_cast<const f16x8*>(&lds[AL + co + arowb + (i << 9)]);
    WAITVM(0);
    BAR();
    LGKM(8);
    __builtin_amdgcn_s_setprio(1);
#pragma unroll
    for (int i = 0; i < 8; i++)
#pragma unroll
      for (int j = 0; j < 4; j++)
        acc[i][j] = __builtin_amdgcn_mfma_f32_16x16x32_f16(ah[i], bl[j], acc[i][j], 0, 0, 0);
    __builtin_amdgcn_s_setprio(0);
    SCHED0();
    if (tt < 31) {
#pragma unroll
      for (int i = 0; i < 8; i++)
        ah[i] = *reinterpret_cast<const f16x8*>(&lds[AH + cn + arowb + (i << 9)]);
      LGKM(8);
    } else {
      LGKM(0);
    }
    __builtin_amdgcn_s_setprio(1);
#pragma unroll
    for (int i = 0; i < 8; i++)
#pragma unroll
      for (int j = 0; j < 4; j++)
        acc[i][j] = __builtin_amdgcn_mfma_f32_16x16x32_f16(al[i], bh[j], acc[i][j], 0, 0, 0);
    __builtin_amdgcn_s_setprio(0);
    SCHED0();
    if (tt < 31) {
#pragma unroll
      for (int j = 0; j < 4; j++)
        bh[j] = *reinterpret_cast<const f16x8*>(&lds[BH + cn + browb + (j << 9)]);
    }
    BAR();
    if (tt < 30) STAGE((tt + 2) << 5, tt & 1);
  }

  int q = lane >> 4, cc = lane & 15;
  int wrowb = mbase + (wy << 7), wcolb = nbase + (wx << 6);
#pragma unroll
  for (int i = 0; i < 8; i++)
#pragma unroll
    for (int r = 0; r < 4; r++) {
      int grow = wrowb + (i << 4) + (q << 2) + r;
      unsigned long long best = 0ull;
#pragma unroll
      for (int j = 0; j < 4; j++) {
        float vv = acc[i][j][r];
        unsigned vb = __float_as_uint(vv);
        vb = (vb & 0x80000000u) ? ~vb : (vb | 0x80000000u);
        unsigned idxn = (unsigned)(wcolb + (j << 4) + cc);
        unsigned long long key = ((unsigned long long)vb << 32) | (unsigned)(~idxn);
        if (key > best) best = key;
      }
      for (int m = 1; m <= 8; m <<= 1) {
        unsigned long long o = shfl_xor_u64(best, m);
        if (o > best) best = o;
      }
      if (cc == 0) atomicMax(keys + grow, best);
    }
}

// ---------------- MAIN: 256x256, 8 waves, 3 LDS bufs, m201-style phase interleave -------------
// Per 32-K tile: 2 phases, each {ds-read subtile; stage-half(tt+2); BAR; lgkm(0);
// setprio(1); 16 MFMA; setprio(0); BAR}. One counted vmcnt(4) per tile (phase 1),
// never 0 until the 2-tile tail. Ledger: at tile tt ph1, outstanding =
// stage(tt+1)[4, oldest] + stage(tt+2)[4] -> vmcnt(4) proves tt+1 staged.
// Buf rotation: tile tt in buf tt%3; stage(tt+2) targets buf (tt+2)%3 whose last
// reader (tile tt-1) finished before its final barrier.
__global__ __launch_bounds__(512, 2) void gemm256_main(
    const unsigned short* __restrict__ Ahi, const unsigned short* __restrict__ Bhi,
    int lda, int ldb, int bkoff, int NT,
    const unsigned long long* __restrict__ keys,
    const float* __restrict__ aproj,
    float* __restrict__ out) {
  __shared__ unsigned short lds[49152];  // 3 bufs x (AH 8192 | BH 8192) ushorts = 96 KB
  constexpr int AH = 0, BH = 8192, BUF = 16384;

  int t = threadIdx.x;
  int bidx = blockIdx.x;
  int xcd = bidx & 7, slot = bidx >> 3;
  int nt = slot % NT, mt = (slot / NT) * 8 + xcd;
  int mbase = mt << 8, nbase = nt << 8;
  int lane = t & 63, wid = t >> 6;
  int wy = wid >> 2, wx = wid & 3;
  int lr = lane & 15;
  int lk2 = (((lane >> 4) ^ ((lane >> 1) & 3)) << 3);

  int srow = (wid << 4) + (lane >> 2);
  int scol = (((lane & 3) ^ ((lane >> 3) & 3)) << 3);
  int wdst = wid << 9;

  const unsigned short* gA = Ahi + (size_t)(mbase + srow) * lda + scol;
  const unsigned short* gB = Bhi + (size_t)(nbase + srow) * ldb + bkoff + scol;
  const size_t a128 = (size_t)128 * lda, b128 = (size_t)128 * ldb;

  auto STAGE_A = [&](int k0v, int b) {
    int co = b * BUF;
    gload16(gA + k0v, &lds[AH + co + wdst]);
    gload16(gA + a128 + k0v, &lds[AH + co + 4096 + wdst]);
  };
  auto STAGE_B = [&](int k0v, int b) {
    int co = b * BUF;
    gload16(gB + k0v, &lds[BH + co + wdst]);
    gload16(gB + b128 + k0v, &lds[BH + co + 4096 + wdst]);
  };

  int arowb = (((wy << 7) + lr) << 5) + lk2;
  int browb = (((wx << 6) + lr) << 5) + lk2;

  f32x4 zero = {0.f, 0.f, 0.f, 0.f};
  f32x4 acc[8][4];
#pragma unroll
  for (int i = 0; i < 8; i++)
#pragma unroll
    for (int j = 0; j < 4; j++) acc[i][j] = zero;

  STAGE_A(0, 0);
  STAGE_B(0, 0);
  STAGE_A(32, 1);
  STAGE_B(32, 1);
  WAITVM(4);  // tile0 staged (tile1's 4 still in flight)
  BAR();

  int cb = 0;  // buf of tile tt
  for (int tt = 0; tt < 32; ++tt) {
    int co = cb * BUF;
    int sb = (cb >= 1) ? cb - 1 : 2;  // buf of tile tt+2 = (cb+2)%3
    int k2 = (tt + 2) << 5;
    f16x8 a0[4], a1[4], bh[4];
    // ---- phase 0: wave-tile rows 0-63 (i = 0..3) ----
#pragma unroll
    for (int i = 0; i < 4; i++)
      a0[i] = *reinterpret_cast<const f16x8*>(&lds[AH + co + arowb + (i << 9)]);
#pragma unroll
    for (int j = 0; j < 4; j++)
      bh[j] = *reinterpret_cast<const f16x8*>(&lds[BH + co + browb + (j << 9)]);
    if (tt < 30) STAGE_A(k2, sb);
    BAR();
    LGKM(0);
    __builtin_amdgcn_s_setprio(1);
#pragma unroll
    for (int i = 0; i < 4; i++)
#pragma unroll
      for (int j = 0; j < 4; j++)
        acc[i][j] = __builtin_amdgcn_mfma_f32_16x16x32_f16(a0[i], bh[j], acc[i][j], 0, 0, 0);
    __builtin_amdgcn_s_setprio(0);
    BAR();
    // ---- phase 1: wave-tile rows 64-127 (i = 4..7) ----
#pragma unroll
    for (int i = 0; i < 4; i++)
      a1[i] = *reinterpret_cast<const f16x8*>(&lds[AH + co + arowb + ((i + 4) << 9)]);
    if (tt < 30) STAGE_B(k2, sb);
    if (tt < 30) { WAITVM(4); } else { WAITVM(0); }
    BAR();  // collective: tile tt+1 staged; lockstep for next phase
    LGKM(0);
    __builtin_amdgcn_s_setprio(1);
#pragma unroll
    for (int i = 0; i < 4; i++)
#pragma unroll
      for (int j = 0; j < 4; j++)
        acc[i + 4][j] = __builtin_amdgcn_mfma_f32_16x16x32_f16(a1[i], bh[j], acc[i + 4][j], 0, 0, 0);
    __builtin_amdgcn_s_setprio(0);
    BAR();  // all waves done reading buf cb this tile
    cb = (cb < 2) ? cb + 1 : 0;
  }

  int q = lane >> 4, cc = lane & 15;
  int wrowb = mbase + (wy << 7), wcolb = nbase + (wx << 6);
#pragma unroll
  for (int i = 0; i < 8; i++)
#pragma unroll
    for (int r = 0; r < 4; r++) {
      int grow = wrowb + (i << 4) + (q << 2) + r;
      unsigned idx = ~(unsigned)(keys[grow] & 0xFFFFFFFFull);
      idx &= 1023u;
      const float* ap = aproj + (size_t)idx * NOUT;
#pragma unroll
      for (int j = 0; j < 4; j++) {
        int gcol = wcolb + (j << 4) + cc;
        out[(size_t)grow * NOUT + gcol] = acc[i][j][r] + ap[gcol];
      }
    }
}

extern "C" void kernel_launch(void* const* d_in, const int* in_sizes, int n_in,
                              void* d_out, int out_size, void* d_ws, size_t ws_size,
                              hipStream_t stream) {
  const float* features = (const float*)d_in[0];
  const float* anchors = (const float*)d_in[1];
  const float* Wout = (const float*)d_in[2];
  float* out = (float*)d_out;

  char* p = (char*)d_ws;
  size_t off = 0;
  auto alloc = [&](size_t b) {
    char* r = p + off;
    off += (b + 255) & ~(size_t)255;
    return r;
  };
  unsigned short* fh = (unsigned short*)alloc((size_t)N_ROWS * HDIM * 2);
  unsigned short* fl = (unsigned short*)alloc((size_t)N_ROWS * HDIM * 2);
  unsigned short* ash = (unsigned short*)alloc((size_t)CPAD * HDIM * 2);
  unsigned short* asl = (unsigned short*)alloc((size_t)CPAD * HDIM * 2);
  unsigned short* anh = (unsigned short*)alloc((size_t)CPAD * HDIM * 2);
  unsigned short* wt = (unsigned short*)alloc((size_t)NOUT * KK2 * 2);
  float* ap = (float*)alloc((size_t)CPAD * NOUT * 4);
  unsigned long long* keys = (unsigned long long*)alloc((size_t)N_ROWS * 8);
  if (off > ws_size) return;

  init_keys_kernel<<<N_ROWS / 256, 256, 0, stream>>>(keys);
  prep_anchors_kernel<<<CPAD, 256, 0, stream>>>(anchors, ash, asl, anh);
  fsplit_kernel<<<(N_ROWS * HDIM / 4) / 256, 256, 0, stream>>>(features, fh, fl);
  wtrans_kernel<<<512, 256, 0, stream>>>(Wout, wt);
  // anchor_proj = class_anchors @ W[0:1024,:] -> ap
  gemm_out_kernel<<<64, 256, 0, stream>>>(anh, wt, HDIM, KK2, 0, 8, ap, NOUT);
  // sim + argmax (3-term fp16 split)
  gemm256_sim<<<512, 512, 0, stream>>>(fh, fl, ash, asl, HDIM, HDIM, 4, keys);
  // out = features @ W[1024:2048,:] + anchor_proj[idx]
  gemm256_main<<<512, 512, 0, stream>>>(fh, wt, HDIM, KK2, HDIM, 4, keys, ap, out);
}